// Round 1
// 429.638 us; speedup vs baseline: 1.2303x; 1.2303x over previous
//
#include <hip/hip_runtime.h>

// SlideMean_Norm: out[b,0,t,f] = x[b,0,t,f] - mean(x[b,0,s:e,f]),
//   s = max(t-150, 0), e = min(t+150, T-1) (end-exclusive).
// Streaming sliding-window sum in registers, float2 columns.
// R1: edge chunks now use the SAME batched-load structure as interior
//     (clamped addresses + 0/1 mask multiplies) -- kills the serial-load
//     straggler tail that dominated the previous version. Batches deepened
//     to 10 rows (30 loads in flight) on both paths.

constexpr int B    = 32;
constexpr int T    = 16000;
constexpr int F    = 80;
constexpr int HALF = 150;          // WIN_LEN / 2
constexpr int CL   = 250;          // chunk length along t
constexpr int NCHUNK = T / CL;     // 64
constexpr int RS   = F / 2;        // row stride in float2 units = 40
constexpr int NCOL2 = B * F / 2;   // 1280 float2-columns (multiple of 64)
constexpr int NTHREADS = NCOL2 * NCHUNK;  // 81920
constexpr int BLOCK = 64;

__global__ __launch_bounds__(BLOCK) void slide_mean_norm(const float2* __restrict__ x,
                                                         float2* __restrict__ out) {
    int tid   = blockIdx.x * BLOCK + threadIdx.x;
    int col2  = tid % NCOL2;        // consecutive lanes -> consecutive float2 (coalesced)
    int chunk = tid / NCOL2;        // wave-uniform
    int b  = col2 / RS;
    int f2 = col2 % RS;

    const float2* xp = x   + (size_t)b * T * RS + f2;
    float2*       op = out + (size_t)b * T * RS + f2;

    int t0 = chunk * CL;
    float sx = 0.f, sy = 0.f;

    bool interior = (t0 >= HALF) && (t0 + CL - 1 + HALF <= T - 1);

    if (interior) {
        // ---- warm-up: exactly 300 rows [t0-150, t0+150), batches of 10 loads ----
        const float2* p = xp + (size_t)(t0 - HALF) * RS;
        #pragma unroll 1
        for (int k = 0; k < 2 * HALF; k += 10) {
            float2 v[10];
            #pragma unroll
            for (int j = 0; j < 10; ++j) v[j] = p[(k + j) * RS];
            #pragma unroll
            for (int j = 0; j < 10; ++j) { sx += v[j].x; sy += v[j].y; }
        }
        // ---- main: branchless, count == 300, 10 iters per round (30 loads in flight) ----
        const float inv = 1.0f / (2.0f * HALF);
        #pragma unroll 1
        for (int i = t0; i < t0 + CL; i += 10) {
            float2 c[10], ld[10], tr[10];
            #pragma unroll
            for (int j = 0; j < 10; ++j) {
                c[j]  = xp[(i + j) * RS];
                ld[j] = xp[(i + j + HALF) * RS];
                tr[j] = xp[(i + j - HALF) * RS];
            }
            #pragma unroll
            for (int j = 0; j < 10; ++j) {
                float ox = c[j].x - sx * inv;
                float oy = c[j].y - sy * inv;
                sx += ld[j].x - tr[j].x;
                sy += ld[j].y - tr[j].y;
                op[(i + j) * RS] = make_float2(ox, oy);
            }
        }
    } else {
        // ---- edge chunks (0 and 63): batched + masked, same pipeline shape ----
        // warm-up: window of i = t0 is [s0, e0), 150 or 300 rows (wave-uniform)
        int s0 = t0 - HALF; if (s0 < 0) s0 = 0;
        int e0 = t0 + HALF; if (e0 > T - 1) e0 = T - 1;
        int k = s0;
        #pragma unroll 1
        for (; k + 10 <= e0; k += 10) {
            float2 v[10];
            #pragma unroll
            for (int j = 0; j < 10; ++j) v[j] = xp[(size_t)(k + j) * RS];
            #pragma unroll
            for (int j = 0; j < 10; ++j) { sx += v[j].x; sy += v[j].y; }
        }
        #pragma unroll 1
        for (; k < e0; ++k) { float2 v = xp[(size_t)k * RS]; sx += v.x; sy += v.y; }

        // main: clamped addresses, 0/1 mask multiplies, per-row 1/(e-s)
        #pragma unroll 1
        for (int i = t0; i < t0 + CL; i += 10) {
            float2 c[10], ld[10], tr[10];
            float lm[10], tm[10];
            #pragma unroll
            for (int j = 0; j < 10; ++j) {
                int t = i + j;
                int lidx = t + HALF;             // add x[t+150] iff t+150 <= T-2
                lm[j] = (lidx <= T - 2) ? 1.0f : 0.0f;
                if (lidx > T - 1) lidx = T - 1;  // clamp: load stays in-bounds
                int tidx = t - HALF;             // sub x[t-150] iff t >= 150
                tm[j] = (tidx >= 0) ? 1.0f : 0.0f;
                if (tidx < 0) tidx = 0;
                c[j]  = xp[(size_t)t * RS];
                ld[j] = xp[(size_t)lidx * RS];
                tr[j] = xp[(size_t)tidx * RS];
            }
            #pragma unroll
            for (int j = 0; j < 10; ++j) {
                int t = i + j;
                int s = t - HALF; if (s < 0) s = 0;
                int e = t + HALF; if (e > T - 1) e = T - 1;
                float inv = 1.0f / (float)(e - s);
                float ox = c[j].x - sx * inv;
                float oy = c[j].y - sy * inv;
                sx += lm[j] * ld[j].x - tm[j] * tr[j].x;
                sy += lm[j] * ld[j].y - tm[j] * tr[j].y;
                op[(size_t)t * RS] = make_float2(ox, oy);
            }
        }
    }
}

extern "C" void kernel_launch(void* const* d_in, const int* in_sizes, int n_in,
                              void* d_out, int out_size, void* d_ws, size_t ws_size,
                              hipStream_t stream) {
    const float2* x = (const float2*)d_in[0];
    float2* out = (float2*)d_out;
    slide_mean_norm<<<dim3(NTHREADS / BLOCK), dim3(BLOCK), 0, stream>>>(x, out);
}